// Round 7
// baseline (257.398 us; speedup 1.0000x reference)
//
#include <hip/hip_runtime.h>

#define DIM 64
#define BSHIFT 8                 // bucket = dst >> 8  (node range 256/bucket)
#define MAXNB 1024               // max coarse buckets (N <= 262144)
#define CHUNK 4096               // edges per block in hist/scatter passes

// ---------------------------------------------------------------------------
// bf16 helpers (OCP bf16 = top 16 bits of fp32, RNE)
// ---------------------------------------------------------------------------
__device__ inline unsigned packbf(float a, float b) {
    unsigned ua = __float_as_uint(a), ub = __float_as_uint(b);
    unsigned ra = (ua + 0x7FFFu + ((ua >> 16) & 1u)) >> 16;
    unsigned rb = (ub + 0x7FFFu + ((ub >> 16) & 1u)) >> 16;
    return ra | (rb << 16);
}
__device__ inline void unpackbf(unsigned u, float& lo, float& hi) {
    lo = __uint_as_float(u << 16);
    hi = __uint_as_float(u & 0xFFFF0000u);
}
// s[0..7] += 8 bf16 (one uint4)
__device__ inline void acc_row(const uint4 v, float* s) {
    float lo, hi;
    unpackbf(v.x, lo, hi); s[0] += lo; s[1] += hi;
    unpackbf(v.y, lo, hi); s[2] += lo; s[3] += hi;
    unpackbf(v.z, lo, hi); s[4] += lo; s[5] += hi;
    unpackbf(v.w, lo, hi); s[6] += lo; s[7] += hi;
}
// s[0..7] += m * (8 bf16)   (m = 0/1 tail mask -> fma, no branch)
__device__ inline void acc_row_m(const uint4 v, float m, float* s) {
    float lo, hi;
    unpackbf(v.x, lo, hi); s[0] = fmaf(m, lo, s[0]); s[1] = fmaf(m, hi, s[1]);
    unpackbf(v.y, lo, hi); s[2] = fmaf(m, lo, s[2]); s[3] = fmaf(m, hi, s[3]);
    unpackbf(v.z, lo, hi); s[4] = fmaf(m, lo, s[4]); s[5] = fmaf(m, hi, s[5]);
    unpackbf(v.w, lo, hi); s[6] = fmaf(m, lo, s[6]); s[7] = fmaf(m, hi, s[7]);
}

// ---------------------------------------------------------------------------
// K1: per-block bucket histogram.  H[k*nblocks + b] = count (bucket-major)
// ---------------------------------------------------------------------------
__global__ __launch_bounds__(256) void block_hist_kernel(
        const int* __restrict__ col, int* __restrict__ H, int E, int NB,
        int nblocks) {
    __shared__ int h[MAXNB];
    int tid = threadIdx.x;
    for (int k = tid; k < NB; k += 256) h[k] = 0;
    __syncthreads();
    int base = blockIdx.x * CHUNK;
    #pragma unroll
    for (int k = 0; k < CHUNK / 256; k++) {
        int e = base + tid + k * 256;
        if (e < E) atomicAdd(&h[col[e] >> BSHIFT], 1);
    }
    __syncthreads();
    for (int k = tid; k < NB; k += 256) H[(size_t)k * nblocks + blockIdx.x] = h[k];
}

// ---------------------------------------------------------------------------
// K2/K3/K4: 3-kernel exclusive scan of H[0..M) -> S ; T = tile sums (<=256)
// K4 also emits bbase[k] = S[k*nblocks] (bucket region starts), bbase[NB]=E
// ---------------------------------------------------------------------------
__global__ void scan_tile_sum_kernel(const int* __restrict__ H,
                                     int* __restrict__ T, int M) {
    int tid = threadIdx.x;
    int base = blockIdx.x * 1024 + tid * 4;
    int s = 0;
    #pragma unroll
    for (int k = 0; k < 4; k++)
        if (base + k < M) s += H[base + k];
    __shared__ int lds[256];
    lds[tid] = s;
    __syncthreads();
    for (int off = 128; off > 0; off >>= 1) {
        if (tid < off) lds[tid] += lds[tid + off];
        __syncthreads();
    }
    if (tid == 0) T[blockIdx.x] = lds[0];
}

__global__ void scan_tile_offsets_kernel(int* __restrict__ T, int nt) {
    __shared__ int lds[256];
    int tid = threadIdx.x;
    int v = (tid < nt) ? T[tid] : 0;
    lds[tid] = v;
    __syncthreads();
    for (int off = 1; off < 256; off <<= 1) {
        int t = (tid >= off) ? lds[tid - off] : 0;
        __syncthreads();
        lds[tid] += t;
        __syncthreads();
    }
    if (tid < nt) T[tid] = lds[tid] - v;  // exclusive
}

__global__ void scan_final_kernel(const int* __restrict__ H,
                                  const int* __restrict__ T,
                                  int* __restrict__ S,
                                  int* __restrict__ bbase, int M, int nblocks,
                                  int NB, int E) {
    int tid = threadIdx.x;
    int base = blockIdx.x * 1024 + tid * 4;
    int c[4];
    int local = 0;
    #pragma unroll
    for (int k = 0; k < 4; k++) {
        c[k] = (base + k < M) ? H[base + k] : 0;
        local += c[k];
    }
    __shared__ int lds[256];
    lds[tid] = local;
    __syncthreads();
    for (int off = 1; off < 256; off <<= 1) {
        int t = (tid >= off) ? lds[tid - off] : 0;
        __syncthreads();
        lds[tid] += t;
        __syncthreads();
    }
    int excl = lds[tid] - local + T[blockIdx.x];
    #pragma unroll
    for (int k = 0; k < 4; k++) {
        int m = base + k;
        if (m < M) {
            S[m] = excl;
            if (m % nblocks == 0) bbase[m / nblocks] = excl;  // bucket start
        }
        excl += c[k];
    }
    if (blockIdx.x == 0 && tid == 0) bbase[NB] = E;
}

// ---------------------------------------------------------------------------
// K5: deterministic binned scatter (bases from S — zero global atomics)
// pairs[pos] = src | (dst_local << 24)
// ---------------------------------------------------------------------------
__global__ __launch_bounds__(256) void scatter_binned_kernel(
        const int* __restrict__ row, const int* __restrict__ col,
        const int* __restrict__ S, unsigned* __restrict__ pairs, int E,
        int NB, int nblocks) {
    __shared__ unsigned stage[CHUNK];
    __shared__ int gdst[CHUNK];
    __shared__ int hist[MAXNB];   // counts -> local cursor
    __shared__ int pfx[MAXNB];    // exclusive local prefix
    __shared__ int gbase[MAXNB];  // per-(block,bucket) base (scan scratch too)
    int tid = threadIdx.x;
    int bid = blockIdx.x;
    int base = bid * CHUNK;
    int nloc = min(CHUNK, E - base);

    for (int b = tid; b < NB; b += 256) hist[b] = 0;
    __syncthreads();

    unsigned vals[CHUNK / 256];
    int keys[CHUNK / 256];
    #pragma unroll
    for (int k = 0; k < CHUNK / 256; k++) {
        int e = base + tid + k * 256;
        if (e < E) {
            int d = col[e];
            int s = row[e];
            keys[k] = d >> BSHIFT;
            vals[k] = (unsigned)s | ((unsigned)(d & 255) << 24);
            atomicAdd(&hist[keys[k]], 1);
        } else {
            keys[k] = -1;
        }
    }
    __syncthreads();

    int b0 = tid * 4;
    int c4[4];
    int loc = 0;
    #pragma unroll
    for (int k = 0; k < 4; k++) {
        c4[k] = (b0 + k < NB) ? hist[b0 + k] : 0;
        loc += c4[k];
    }
    gbase[tid] = loc;
    __syncthreads();
    for (int off = 1; off < 256; off <<= 1) {
        int t = (tid >= off) ? gbase[tid - off] : 0;
        __syncthreads();
        gbase[tid] += t;
        __syncthreads();
    }
    int excl = gbase[tid] - loc;
    #pragma unroll
    for (int k = 0; k < 4; k++) {
        if (b0 + k < NB) pfx[b0 + k] = excl;
        excl += c4[k];
    }
    __syncthreads();

    for (int b = tid; b < NB; b += 256) {
        gbase[b] = S[(size_t)b * nblocks + bid];
        hist[b] = pfx[b];
    }
    __syncthreads();

    #pragma unroll
    for (int k = 0; k < CHUNK / 256; k++) {
        if (keys[k] >= 0) {
            int slot = atomicAdd(&hist[keys[k]], 1);
            stage[slot] = vals[k];
            gdst[slot] = gbase[keys[k]] + (slot - pfx[keys[k]]);
        }
    }
    __syncthreads();

    for (int s = tid; s < nloc; s += 256) pairs[gdst[s]] = stage[s];
}

// ---------------------------------------------------------------------------
// K6: fine fill — one workgroup per bucket; LDS count/scan/cursors;
// produces row_ptr (degree = diff) and dst-grouped csr_src.
// ---------------------------------------------------------------------------
__global__ void fine_fill_kernel(const unsigned* __restrict__ pairs,
                                 const int* __restrict__ bbase,
                                 int* __restrict__ row_ptr,
                                 int* __restrict__ csr_src, int N, int E) {
    __shared__ int cnt[256];
    __shared__ int cur[256];
    int b = blockIdx.x;
    int tid = threadIdx.x;
    int beg = bbase[b], end = bbase[b + 1];
    cnt[tid] = 0;
    __syncthreads();
    for (int j = beg + tid; j < end; j += 256)
        atomicAdd(&cnt[pairs[j] >> 24], 1);
    __syncthreads();
    int v = cnt[tid];
    for (int off = 1; off < 256; off <<= 1) {
        int t = (tid >= off) ? cnt[tid - off] : 0;
        __syncthreads();
        cnt[tid] += t;
        __syncthreads();
    }
    int excl = cnt[tid] - v;
    int node = (b << BSHIFT) + tid;
    if (node < N) row_ptr[node] = beg + excl;
    cur[tid] = beg + excl;
    __syncthreads();
    for (int j = beg + tid; j < end; j += 256) {
        unsigned p = pairs[j];
        int pos = atomicAdd(&cur[p >> 24], 1);
        csr_src[pos] = (int)(p & 0xFFFFFFu);
    }
    if (b == 0 && tid == 0) row_ptr[N] = E;
}

// ---------------------------------------------------------------------------
// prescale: z0 = deg^{-1/2} * emb (bf16) AND embb = emb (bf16)
// 8-lane group per node
// ---------------------------------------------------------------------------
__global__ void prescale_kernel(const float4* __restrict__ emb4,
                                const int* __restrict__ row_ptr,
                                uint4* __restrict__ z4,
                                uint4* __restrict__ embb, int N) {
    int t = blockIdx.x * blockDim.x + threadIdx.x;
    int i = t >> 3;
    int gl = t & 7;
    if (i >= N) return;
    int deg = row_ptr[i + 1] - row_ptr[i];
    float wd = (deg > 0) ? rsqrtf((float)deg) : 0.0f;
    size_t eo = (size_t)i * 16 + gl * 2;
    float4 a = emb4[eo], b = emb4[eo + 1];
    size_t zo = (size_t)i * 8 + gl;
    uint4 eb;
    eb.x = packbf(a.x, a.y);
    eb.y = packbf(a.z, a.w);
    eb.z = packbf(b.x, b.y);
    eb.w = packbf(b.z, b.w);
    embb[zo] = eb;
    uint4 z;
    z.x = packbf(a.x * wd, a.y * wd);
    z.y = packbf(a.z * wd, a.w * wd);
    z.z = packbf(b.x * wd, b.y * wd);
    z.w = packbf(b.z * wd, b.w * wd);
    z4[zo] = z;
}

// ---------------------------------------------------------------------------
// software-pipelined gather-sum over one CSR row (8-lane group)
// ---------------------------------------------------------------------------
__device__ inline void row_gather_sum(const int* __restrict__ csr_src,
                                      const uint4* __restrict__ z4, int b,
                                      int e, int gl, float* s) {
    if (b >= e) return;
    int e1 = e - 1;
    int j = b;
    int i0 = csr_src[j];
    int i1 = csr_src[min(j + 1, e1)];
    int i2 = csr_src[min(j + 2, e1)];
    int i3 = csr_src[min(j + 3, e1)];
    while (j < e) {
        uint4 v0 = z4[(size_t)i0 * 8 + gl];
        uint4 v1 = z4[(size_t)i1 * 8 + gl];
        uint4 v2 = z4[(size_t)i2 * 8 + gl];
        uint4 v3 = z4[(size_t)i3 * 8 + gl];
        int jn = j + 4;
        if (jn < e) {
            i0 = csr_src[jn];
            i1 = csr_src[min(jn + 1, e1)];
            i2 = csr_src[min(jn + 2, e1)];
            i3 = csr_src[min(jn + 3, e1)];
        }
        float m1 = (j + 1 < e) ? 1.0f : 0.0f;
        float m2 = (j + 2 < e) ? 1.0f : 0.0f;
        float m3 = (j + 3 < e) ? 1.0f : 0.0f;
        acc_row(v0, s);
        acc_row_m(v1, m1, s);
        acc_row_m(v2, m2, s);
        acc_row_m(v3, m3, s);
        j = jn;
    }
}

// ---------------------------------------------------------------------------
// pull SpMM on bf16 z:  z_next[i] = (sum z[src]) / deg
// 64-thread (1-wave) blocks: 8 nodes/block, waves retire independently
// ---------------------------------------------------------------------------
__global__ __launch_bounds__(64) void spmm_pull_kernel(
        const int* __restrict__ row_ptr, const int* __restrict__ csr_src,
        const uint4* __restrict__ z4, uint4* __restrict__ znext4, int N) {
    int t = blockIdx.x * 64 + threadIdx.x;
    int i = t >> 3;
    int gl = t & 7;
    if (i >= N) return;
    int b = row_ptr[i], e = row_ptr[i + 1];
    float s[8] = {0, 0, 0, 0, 0, 0, 0, 0};
    row_gather_sum(csr_src, z4, b, e, gl, s);
    int deg = e - b;
    float wd = (deg > 0) ? rsqrtf((float)deg) : 0.0f;
    float w2 = wd * wd;
    uint4 z;
    z.x = packbf(s[0] * w2, s[1] * w2);
    z.y = packbf(s[2] * w2, s[3] * w2);
    z.z = packbf(s[4] * w2, s[5] * w2);
    z.w = packbf(s[6] * w2, s[7] * w2);
    znext4[(size_t)i * 8 + gl] = z;
}

// ---------------------------------------------------------------------------
// fused layer-3 SpMM + combine:
//   t = sum_{nbr} z2[src];  acc = embb + sqrt(deg)*(z1+z2) + wd*t   (bf16)
// ---------------------------------------------------------------------------
__global__ __launch_bounds__(64) void spmm_combine_kernel(
        const int* __restrict__ row_ptr, const int* __restrict__ csr_src,
        const uint4* __restrict__ z2, const uint4* __restrict__ z1,
        const uint4* __restrict__ embb, uint4* __restrict__ accb, int N) {
    int t = blockIdx.x * 64 + threadIdx.x;
    int i = t >> 3;
    int gl = t & 7;
    if (i >= N) return;
    int b = row_ptr[i], e = row_ptr[i + 1];
    float s[8] = {0, 0, 0, 0, 0, 0, 0, 0};
    row_gather_sum(csr_src, z2, b, e, gl, s);
    int deg = e - b;
    float wd = (deg > 0) ? rsqrtf((float)deg) : 0.0f;
    float sq = (deg > 0) ? sqrtf((float)deg) : 0.0f;
    size_t zo = (size_t)i * 8 + gl;
    uint4 a1 = z1[zo], a2 = z2[zo];
    float w[8] = {0, 0, 0, 0, 0, 0, 0, 0};
    acc_row(a1, w); acc_row(a2, w);
    uint4 eb = embb[zo];
    float em[8] = {0, 0, 0, 0, 0, 0, 0, 0};
    acc_row(eb, em);
    float r[8];
    #pragma unroll
    for (int k = 0; k < 8; k++) r[k] = em[k] + sq * w[k] + wd * s[k];
    uint4 z;
    z.x = packbf(r[0], r[1]);
    z.y = packbf(r[2], r[3]);
    z.z = packbf(r[4], r[5]);
    z.w = packbf(r[6], r[7]);
    accb[zo] = z;
}

// ---------------------------------------------------------------------------
// logits[p] = alpha^2 * dot(acc[u], acc[i])
// 8-lane group per TWO pairs (4 gathers in flight); 1-wave blocks
// ---------------------------------------------------------------------------
__global__ __launch_bounds__(64) void score_kernel(
        const int* __restrict__ batch, const uint4* __restrict__ accb,
        float* __restrict__ out, int P) {
    int t = blockIdx.x * 64 + threadIdx.x;
    int g = t >> 3;
    int gl = t & 7;
    int p0 = g * 2;
    if (p0 >= P) return;
    int p1 = min(p0 + 1, P - 1);
    int u0 = batch[(size_t)p0 * 3 + 0];
    int i0 = batch[(size_t)p0 * 3 + 1];
    int u1 = batch[(size_t)p1 * 3 + 0];
    int i1 = batch[(size_t)p1 * 3 + 1];
    uint4 a0 = accb[(size_t)u0 * 8 + gl];
    uint4 b0 = accb[(size_t)i0 * 8 + gl];
    uint4 a1 = accb[(size_t)u1 * 8 + gl];
    uint4 b1 = accb[(size_t)i1 * 8 + gl];
    float sa[8], sb[8];
    #pragma unroll
    for (int k = 0; k < 8; k++) { sa[k] = 0; sb[k] = 0; }
    acc_row(a0, sa);
    acc_row(b0, sb);
    float s0 = sa[0] * sb[0] + sa[1] * sb[1] + sa[2] * sb[2] + sa[3] * sb[3] +
               sa[4] * sb[4] + sa[5] * sb[5] + sa[6] * sb[6] + sa[7] * sb[7];
    #pragma unroll
    for (int k = 0; k < 8; k++) { sa[k] = 0; sb[k] = 0; }
    acc_row(a1, sa);
    acc_row(b1, sb);
    float s1 = sa[0] * sb[0] + sa[1] * sb[1] + sa[2] * sb[2] + sa[3] * sb[3] +
               sa[4] * sb[4] + sa[5] * sb[5] + sa[6] * sb[6] + sa[7] * sb[7];
    s0 += __shfl_xor(s0, 4, 64);
    s0 += __shfl_xor(s0, 2, 64);
    s0 += __shfl_xor(s0, 1, 64);
    s1 += __shfl_xor(s1, 4, 64);
    s1 += __shfl_xor(s1, 2, 64);
    s1 += __shfl_xor(s1, 1, 64);
    if (gl == 0) {
        out[p0] = s0 * 0.0625f;  // alpha^2, alpha = 1/(K_LAYERS+1)
        if (p0 + 1 < P) out[p0 + 1] = s1 * 0.0625f;
    }
}

extern "C" void kernel_launch(void* const* d_in, const int* in_sizes, int n_in,
                              void* d_out, int out_size, void* d_ws,
                              size_t ws_size, hipStream_t stream) {
    const float* emb = (const float*)d_in[0];
    const int* edge_index = (const int*)d_in[1];
    const int* batch = (const int*)d_in[2];
    float* out = (float*)d_out;

    const int N = in_sizes[0] / DIM;        // 200000
    const int E = in_sizes[1] / 2;          // 1250000
    const int P = out_size;                 // 4096 * 101
    const int NB = (N + 255) >> BSHIFT;     // 782 coarse buckets
    const int nblocks = (E + CHUNK - 1) / CHUNK;  // 306 edge chunks
    const int M = NB * nblocks;             // 239292 scan entries
    const int nt = (M + 1023) / 1024;       // 234 scan tiles (<=256)

    const int* row = edge_index;            // sources
    const int* col = edge_index + E;        // targets

    const size_t zbytes = (size_t)N * DIM * 2;  // bf16 row buffer (25.6 MB)

    auto align256 = [](size_t x) { return (x + 255) & ~(size_t)255; };
    char* ws = (char*)d_ws;
    uint4* z0   = (uint4*)ws; ws += align256(zbytes);
    uint4* z1   = (uint4*)ws; ws += align256(zbytes);
    uint4* z2   = (uint4*)ws; ws += align256(zbytes);
    uint4* accb = (uint4*)ws; ws += align256(zbytes);
    uint4* embb = (uint4*)ws; ws += align256(zbytes);
    unsigned* pairs = (unsigned*)ws; ws += align256((size_t)E * 4);
    int* csr_src    = (int*)ws;      ws += align256((size_t)E * 4);
    int* row_ptr    = (int*)ws;      ws += align256((size_t)(N + 1) * 4);
    int* H          = (int*)ws;      ws += align256((size_t)M * 4);
    int* S          = (int*)ws;      ws += align256((size_t)M * 4);
    int* T          = (int*)ws;      ws += align256(256 * 4);
    int* bbase      = (int*)ws;

    // --- deterministic radix CSR build (no memsets, no global atomics) ---
    block_hist_kernel<<<nblocks, 256, 0, stream>>>(col, H, E, NB, nblocks);
    scan_tile_sum_kernel<<<nt, 256, 0, stream>>>(H, T, M);
    scan_tile_offsets_kernel<<<1, 256, 0, stream>>>(T, nt);
    scan_final_kernel<<<nt, 256, 0, stream>>>(H, T, S, bbase, M, nblocks, NB, E);
    scatter_binned_kernel<<<nblocks, 256, 0, stream>>>(row, col, S, pairs, E,
                                                       NB, nblocks);
    fine_fill_kernel<<<NB, 256, 0, stream>>>(pairs, bbase, row_ptr, csr_src,
                                             N, E);

    // z0 = deg^{-1/2} * emb ; embb = bf16(emb)
    const int nodeBlocks256 = (N * 8 + 255) / 256;
    prescale_kernel<<<nodeBlocks256, 256, 0, stream>>>((const float4*)emb,
                                                       row_ptr, z0, embb, N);

    // --- layers 1,2 pull-SpMM; layer 3 fused with combine (1-wave blocks) ---
    const int waveBlocks = (N + 7) / 8;  // 8 nodes per 64-thread block
    spmm_pull_kernel<<<waveBlocks, 64, 0, stream>>>(row_ptr, csr_src, z0, z1, N);
    spmm_pull_kernel<<<waveBlocks, 64, 0, stream>>>(row_ptr, csr_src, z1, z2, N);
    spmm_combine_kernel<<<waveBlocks, 64, 0, stream>>>(row_ptr, csr_src, z2,
                                                       z1, embb, accb, N);

    // --- scoring: 2 pairs per 8-lane group ---
    const int scoreBlocks = (P + 15) / 16;  // 16 pairs per 64-thread block
    score_kernel<<<scoreBlocks, 64, 0, stream>>>(batch, accb, out, P);
}

// Round 8
// 256.846 us; speedup vs baseline: 1.0022x; 1.0022x over previous
//
#include <hip/hip_runtime.h>

#define DIM 64
#define BSHIFT 8                 // bucket = dst >> 8  (node range 256/bucket)
#define MAXNB 1024               // max coarse buckets (N <= 262144)
#define CHUNK 4096               // edges per block in hist/scatter passes

// ---------------------------------------------------------------------------
// bf16 helpers (OCP bf16 = top 16 bits of fp32, RNE)
// ---------------------------------------------------------------------------
__device__ inline unsigned packbf(float a, float b) {
    unsigned ua = __float_as_uint(a), ub = __float_as_uint(b);
    unsigned ra = (ua + 0x7FFFu + ((ua >> 16) & 1u)) >> 16;
    unsigned rb = (ub + 0x7FFFu + ((ub >> 16) & 1u)) >> 16;
    return ra | (rb << 16);
}
__device__ inline void unpackbf(unsigned u, float& lo, float& hi) {
    lo = __uint_as_float(u << 16);
    hi = __uint_as_float(u & 0xFFFF0000u);
}
// s[0..7] += 8 bf16 (one uint4)
__device__ inline void acc_row(const uint4 v, float* s) {
    float lo, hi;
    unpackbf(v.x, lo, hi); s[0] += lo; s[1] += hi;
    unpackbf(v.y, lo, hi); s[2] += lo; s[3] += hi;
    unpackbf(v.z, lo, hi); s[4] += lo; s[5] += hi;
    unpackbf(v.w, lo, hi); s[6] += lo; s[7] += hi;
}
// s[0..7] += m * (8 bf16)   (m = 0/1 tail mask -> fma, no branch)
__device__ inline void acc_row_m(const uint4 v, float m, float* s) {
    float lo, hi;
    unpackbf(v.x, lo, hi); s[0] = fmaf(m, lo, s[0]); s[1] = fmaf(m, hi, s[1]);
    unpackbf(v.y, lo, hi); s[2] = fmaf(m, lo, s[2]); s[3] = fmaf(m, hi, s[3]);
    unpackbf(v.z, lo, hi); s[4] = fmaf(m, lo, s[4]); s[5] = fmaf(m, hi, s[5]);
    unpackbf(v.w, lo, hi); s[6] = fmaf(m, lo, s[6]); s[7] = fmaf(m, hi, s[7]);
}

// ---------------------------------------------------------------------------
// K1: per-block bucket histogram.  H[k*nblocks + b] = count (bucket-major)
// ---------------------------------------------------------------------------
__global__ __launch_bounds__(256) void block_hist_kernel(
        const int* __restrict__ col, int* __restrict__ H, int E, int NB,
        int nblocks) {
    __shared__ int h[MAXNB];
    int tid = threadIdx.x;
    for (int k = tid; k < NB; k += 256) h[k] = 0;
    __syncthreads();
    int base = blockIdx.x * CHUNK;
    #pragma unroll
    for (int k = 0; k < CHUNK / 256; k++) {
        int e = base + tid + k * 256;
        if (e < E) atomicAdd(&h[col[e] >> BSHIFT], 1);
    }
    __syncthreads();
    for (int k = tid; k < NB; k += 256) H[(size_t)k * nblocks + blockIdx.x] = h[k];
}

// ---------------------------------------------------------------------------
// K2/K3/K4: 3-kernel exclusive scan of H[0..M) -> S ; T = tile sums (<=256)
// K4 also emits bbase[k] = S[k*nblocks] (bucket region starts), bbase[NB]=E
// ---------------------------------------------------------------------------
__global__ void scan_tile_sum_kernel(const int* __restrict__ H,
                                     int* __restrict__ T, int M) {
    int tid = threadIdx.x;
    int base = blockIdx.x * 1024 + tid * 4;
    int s = 0;
    #pragma unroll
    for (int k = 0; k < 4; k++)
        if (base + k < M) s += H[base + k];
    __shared__ int lds[256];
    lds[tid] = s;
    __syncthreads();
    for (int off = 128; off > 0; off >>= 1) {
        if (tid < off) lds[tid] += lds[tid + off];
        __syncthreads();
    }
    if (tid == 0) T[blockIdx.x] = lds[0];
}

__global__ void scan_tile_offsets_kernel(int* __restrict__ T, int nt) {
    __shared__ int lds[256];
    int tid = threadIdx.x;
    int v = (tid < nt) ? T[tid] : 0;
    lds[tid] = v;
    __syncthreads();
    for (int off = 1; off < 256; off <<= 1) {
        int t = (tid >= off) ? lds[tid - off] : 0;
        __syncthreads();
        lds[tid] += t;
        __syncthreads();
    }
    if (tid < nt) T[tid] = lds[tid] - v;  // exclusive
}

__global__ void scan_final_kernel(const int* __restrict__ H,
                                  const int* __restrict__ T,
                                  int* __restrict__ S,
                                  int* __restrict__ bbase, int M, int nblocks,
                                  int NB, int E) {
    int tid = threadIdx.x;
    int base = blockIdx.x * 1024 + tid * 4;
    int c[4];
    int local = 0;
    #pragma unroll
    for (int k = 0; k < 4; k++) {
        c[k] = (base + k < M) ? H[base + k] : 0;
        local += c[k];
    }
    __shared__ int lds[256];
    lds[tid] = local;
    __syncthreads();
    for (int off = 1; off < 256; off <<= 1) {
        int t = (tid >= off) ? lds[tid - off] : 0;
        __syncthreads();
        lds[tid] += t;
        __syncthreads();
    }
    int excl = lds[tid] - local + T[blockIdx.x];
    #pragma unroll
    for (int k = 0; k < 4; k++) {
        int m = base + k;
        if (m < M) {
            S[m] = excl;
            if (m % nblocks == 0) bbase[m / nblocks] = excl;  // bucket start
        }
        excl += c[k];
    }
    if (blockIdx.x == 0 && tid == 0) bbase[NB] = E;
}

// ---------------------------------------------------------------------------
// K5: deterministic binned scatter (bases from S — zero global atomics)
// pairs[pos] = src | (dst_local << 24)
// ---------------------------------------------------------------------------
__global__ __launch_bounds__(256) void scatter_binned_kernel(
        const int* __restrict__ row, const int* __restrict__ col,
        const int* __restrict__ S, unsigned* __restrict__ pairs, int E,
        int NB, int nblocks) {
    __shared__ unsigned stage[CHUNK];
    __shared__ int gdst[CHUNK];
    __shared__ int hist[MAXNB];   // counts -> local cursor
    __shared__ int pfx[MAXNB];    // exclusive local prefix
    __shared__ int gbase[MAXNB];  // per-(block,bucket) base (scan scratch too)
    int tid = threadIdx.x;
    int bid = blockIdx.x;
    int base = bid * CHUNK;
    int nloc = min(CHUNK, E - base);

    for (int b = tid; b < NB; b += 256) hist[b] = 0;
    __syncthreads();

    unsigned vals[CHUNK / 256];
    int keys[CHUNK / 256];
    #pragma unroll
    for (int k = 0; k < CHUNK / 256; k++) {
        int e = base + tid + k * 256;
        if (e < E) {
            int d = col[e];
            int s = row[e];
            keys[k] = d >> BSHIFT;
            vals[k] = (unsigned)s | ((unsigned)(d & 255) << 24);
            atomicAdd(&hist[keys[k]], 1);
        } else {
            keys[k] = -1;
        }
    }
    __syncthreads();

    int b0 = tid * 4;
    int c4[4];
    int loc = 0;
    #pragma unroll
    for (int k = 0; k < 4; k++) {
        c4[k] = (b0 + k < NB) ? hist[b0 + k] : 0;
        loc += c4[k];
    }
    gbase[tid] = loc;
    __syncthreads();
    for (int off = 1; off < 256; off <<= 1) {
        int t = (tid >= off) ? gbase[tid - off] : 0;
        __syncthreads();
        gbase[tid] += t;
        __syncthreads();
    }
    int excl = gbase[tid] - loc;
    #pragma unroll
    for (int k = 0; k < 4; k++) {
        if (b0 + k < NB) pfx[b0 + k] = excl;
        excl += c4[k];
    }
    __syncthreads();

    for (int b = tid; b < NB; b += 256) {
        gbase[b] = S[(size_t)b * nblocks + bid];
        hist[b] = pfx[b];
    }
    __syncthreads();

    #pragma unroll
    for (int k = 0; k < CHUNK / 256; k++) {
        if (keys[k] >= 0) {
            int slot = atomicAdd(&hist[keys[k]], 1);
            stage[slot] = vals[k];
            gdst[slot] = gbase[keys[k]] + (slot - pfx[keys[k]]);
        }
    }
    __syncthreads();

    for (int s = tid; s < nloc; s += 256) pairs[gdst[s]] = stage[s];
}

// ---------------------------------------------------------------------------
// K6: fine fill + fused prescale.
// One workgroup per bucket (256 nodes): LDS count/scan/cursors produce
// row_ptr + dst-grouped csr_src.  Degrees are already in registers/LDS, so
// the block also emits z0 = deg^{-1/2}*emb (bf16) and embb = bf16(emb) for
// its node range — deletes the separate prescale pass.
// ---------------------------------------------------------------------------
__global__ __launch_bounds__(256) void fine_fill_kernel(
        const unsigned* __restrict__ pairs, const int* __restrict__ bbase,
        const float4* __restrict__ emb4, int* __restrict__ row_ptr,
        int* __restrict__ csr_src, uint4* __restrict__ z0,
        uint4* __restrict__ embb, int N, int E) {
    __shared__ int cnt[256];
    __shared__ int cur[256];
    __shared__ int degs[256];
    int b = blockIdx.x;
    int tid = threadIdx.x;
    int beg = bbase[b], end = bbase[b + 1];
    cnt[tid] = 0;
    __syncthreads();
    for (int j = beg + tid; j < end; j += 256)
        atomicAdd(&cnt[pairs[j] >> 24], 1);
    __syncthreads();
    int v = cnt[tid];
    degs[tid] = v;
    for (int off = 1; off < 256; off <<= 1) {
        int t = (tid >= off) ? cnt[tid - off] : 0;
        __syncthreads();
        cnt[tid] += t;
        __syncthreads();
    }
    int excl = cnt[tid] - v;
    int node = (b << BSHIFT) + tid;
    if (node < N) row_ptr[node] = beg + excl;
    cur[tid] = beg + excl;
    __syncthreads();
    for (int j = beg + tid; j < end; j += 256) {
        unsigned p = pairs[j];
        int pos = atomicAdd(&cur[p >> 24], 1);
        csr_src[pos] = (int)(p & 0xFFFFFFu);
    }
    if (b == 0 && tid == 0) row_ptr[N] = E;

    // fused prescale for this bucket's 256 nodes (8-lane groups, 8 rounds)
    int nbase = b << BSHIFT;
    #pragma unroll
    for (int it = 0; it < 8; it++) {
        int idx = it * 256 + tid;          // 0..2047
        int il = idx >> 3;                 // local node 0..255
        int gl = idx & 7;
        int i = nbase + il;
        if (i < N) {
            int deg = degs[il];
            float wd = (deg > 0) ? rsqrtf((float)deg) : 0.0f;
            size_t eo = (size_t)i * 16 + gl * 2;
            float4 a = emb4[eo], c = emb4[eo + 1];
            size_t zo = (size_t)i * 8 + gl;
            uint4 eb;
            eb.x = packbf(a.x, a.y);
            eb.y = packbf(a.z, a.w);
            eb.z = packbf(c.x, c.y);
            eb.w = packbf(c.z, c.w);
            embb[zo] = eb;
            uint4 z;
            z.x = packbf(a.x * wd, a.y * wd);
            z.y = packbf(a.z * wd, a.w * wd);
            z.z = packbf(c.x * wd, c.y * wd);
            z.w = packbf(c.z * wd, c.w * wd);
            z0[zo] = z;
        }
    }
}

// ---------------------------------------------------------------------------
// software-pipelined gather-sum over one CSR row (8-lane group)
// ---------------------------------------------------------------------------
__device__ inline void row_gather_sum(const int* __restrict__ csr_src,
                                      const uint4* __restrict__ z4, int b,
                                      int e, int gl, float* s) {
    if (b >= e) return;
    int e1 = e - 1;
    int j = b;
    int i0 = csr_src[j];
    int i1 = csr_src[min(j + 1, e1)];
    int i2 = csr_src[min(j + 2, e1)];
    int i3 = csr_src[min(j + 3, e1)];
    while (j < e) {
        uint4 v0 = z4[(size_t)i0 * 8 + gl];
        uint4 v1 = z4[(size_t)i1 * 8 + gl];
        uint4 v2 = z4[(size_t)i2 * 8 + gl];
        uint4 v3 = z4[(size_t)i3 * 8 + gl];
        int jn = j + 4;
        if (jn < e) {
            i0 = csr_src[jn];
            i1 = csr_src[min(jn + 1, e1)];
            i2 = csr_src[min(jn + 2, e1)];
            i3 = csr_src[min(jn + 3, e1)];
        }
        float m1 = (j + 1 < e) ? 1.0f : 0.0f;
        float m2 = (j + 2 < e) ? 1.0f : 0.0f;
        float m3 = (j + 3 < e) ? 1.0f : 0.0f;
        acc_row(v0, s);
        acc_row_m(v1, m1, s);
        acc_row_m(v2, m2, s);
        acc_row_m(v3, m3, s);
        j = jn;
    }
}

// ---------------------------------------------------------------------------
// pull SpMM on bf16 z:  z_next[i] = (sum z[src]) / deg
// 256-thread blocks (32 groups): ~8 blocks/CU -> max resident waves
// ---------------------------------------------------------------------------
__global__ __launch_bounds__(256) void spmm_pull_kernel(
        const int* __restrict__ row_ptr, const int* __restrict__ csr_src,
        const uint4* __restrict__ z4, uint4* __restrict__ znext4, int N) {
    int t = blockIdx.x * 256 + threadIdx.x;
    int i = t >> 3;
    int gl = t & 7;
    if (i >= N) return;
    int b = row_ptr[i], e = row_ptr[i + 1];
    float s[8] = {0, 0, 0, 0, 0, 0, 0, 0};
    row_gather_sum(csr_src, z4, b, e, gl, s);
    int deg = e - b;
    float wd = (deg > 0) ? rsqrtf((float)deg) : 0.0f;
    float w2 = wd * wd;
    uint4 z;
    z.x = packbf(s[0] * w2, s[1] * w2);
    z.y = packbf(s[2] * w2, s[3] * w2);
    z.z = packbf(s[4] * w2, s[5] * w2);
    z.w = packbf(s[6] * w2, s[7] * w2);
    znext4[(size_t)i * 8 + gl] = z;
}

// ---------------------------------------------------------------------------
// fused layer-3 SpMM + combine:
//   t = sum_{nbr} z2[src];  acc = embb + sqrt(deg)*(z1+z2) + wd*t   (bf16)
// ---------------------------------------------------------------------------
__global__ __launch_bounds__(256) void spmm_combine_kernel(
        const int* __restrict__ row_ptr, const int* __restrict__ csr_src,
        const uint4* __restrict__ z2, const uint4* __restrict__ z1,
        const uint4* __restrict__ embb, uint4* __restrict__ accb, int N) {
    int t = blockIdx.x * 256 + threadIdx.x;
    int i = t >> 3;
    int gl = t & 7;
    if (i >= N) return;
    int b = row_ptr[i], e = row_ptr[i + 1];
    float s[8] = {0, 0, 0, 0, 0, 0, 0, 0};
    row_gather_sum(csr_src, z2, b, e, gl, s);
    int deg = e - b;
    float wd = (deg > 0) ? rsqrtf((float)deg) : 0.0f;
    float sq = (deg > 0) ? sqrtf((float)deg) : 0.0f;
    size_t zo = (size_t)i * 8 + gl;
    uint4 a1 = z1[zo], a2 = z2[zo];
    float w[8] = {0, 0, 0, 0, 0, 0, 0, 0};
    acc_row(a1, w); acc_row(a2, w);
    uint4 eb = embb[zo];
    float em[8] = {0, 0, 0, 0, 0, 0, 0, 0};
    acc_row(eb, em);
    float r[8];
    #pragma unroll
    for (int k = 0; k < 8; k++) r[k] = em[k] + sq * w[k] + wd * s[k];
    uint4 z;
    z.x = packbf(r[0], r[1]);
    z.y = packbf(r[2], r[3]);
    z.z = packbf(r[4], r[5]);
    z.w = packbf(r[6], r[7]);
    accb[zo] = z;
}

// ---------------------------------------------------------------------------
// logits[p] = alpha^2 * dot(acc[u], acc[i])
// 8-lane group per TWO pairs (4 gathers in flight); 256-thread blocks
// ---------------------------------------------------------------------------
__global__ __launch_bounds__(256) void score_kernel(
        const int* __restrict__ batch, const uint4* __restrict__ accb,
        float* __restrict__ out, int P) {
    int t = blockIdx.x * 256 + threadIdx.x;
    int g = t >> 3;
    int gl = t & 7;
    int p0 = g * 2;
    if (p0 >= P) return;
    int p1 = min(p0 + 1, P - 1);
    int u0 = batch[(size_t)p0 * 3 + 0];
    int i0 = batch[(size_t)p0 * 3 + 1];
    int u1 = batch[(size_t)p1 * 3 + 0];
    int i1 = batch[(size_t)p1 * 3 + 1];
    uint4 a0 = accb[(size_t)u0 * 8 + gl];
    uint4 b0 = accb[(size_t)i0 * 8 + gl];
    uint4 a1 = accb[(size_t)u1 * 8 + gl];
    uint4 b1 = accb[(size_t)i1 * 8 + gl];
    float sa[8], sb[8];
    #pragma unroll
    for (int k = 0; k < 8; k++) { sa[k] = 0; sb[k] = 0; }
    acc_row(a0, sa);
    acc_row(b0, sb);
    float s0 = sa[0] * sb[0] + sa[1] * sb[1] + sa[2] * sb[2] + sa[3] * sb[3] +
               sa[4] * sb[4] + sa[5] * sb[5] + sa[6] * sb[6] + sa[7] * sb[7];
    #pragma unroll
    for (int k = 0; k < 8; k++) { sa[k] = 0; sb[k] = 0; }
    acc_row(a1, sa);
    acc_row(b1, sb);
    float s1 = sa[0] * sb[0] + sa[1] * sb[1] + sa[2] * sb[2] + sa[3] * sb[3] +
               sa[4] * sb[4] + sa[5] * sb[5] + sa[6] * sb[6] + sa[7] * sb[7];
    s0 += __shfl_xor(s0, 4, 64);
    s0 += __shfl_xor(s0, 2, 64);
    s0 += __shfl_xor(s0, 1, 64);
    s1 += __shfl_xor(s1, 4, 64);
    s1 += __shfl_xor(s1, 2, 64);
    s1 += __shfl_xor(s1, 1, 64);
    if (gl == 0) {
        out[p0] = s0 * 0.0625f;  // alpha^2, alpha = 1/(K_LAYERS+1)
        if (p0 + 1 < P) out[p0 + 1] = s1 * 0.0625f;
    }
}

extern "C" void kernel_launch(void* const* d_in, const int* in_sizes, int n_in,
                              void* d_out, int out_size, void* d_ws,
                              size_t ws_size, hipStream_t stream) {
    const float* emb = (const float*)d_in[0];
    const int* edge_index = (const int*)d_in[1];
    const int* batch = (const int*)d_in[2];
    float* out = (float*)d_out;

    const int N = in_sizes[0] / DIM;        // 200000
    const int E = in_sizes[1] / 2;          // 1250000
    const int P = out_size;                 // 4096 * 101
    const int NB = (N + 255) >> BSHIFT;     // 782 coarse buckets
    const int nblocks = (E + CHUNK - 1) / CHUNK;  // 306 edge chunks
    const int M = NB * nblocks;             // 239292 scan entries
    const int nt = (M + 1023) / 1024;       // 234 scan tiles (<=256)

    const int* row = edge_index;            // sources
    const int* col = edge_index + E;        // targets

    const size_t zbytes = (size_t)N * DIM * 2;  // bf16 row buffer (25.6 MB)

    auto align256 = [](size_t x) { return (x + 255) & ~(size_t)255; };
    char* ws = (char*)d_ws;
    uint4* z0   = (uint4*)ws; ws += align256(zbytes);
    uint4* z1   = (uint4*)ws; ws += align256(zbytes);
    uint4* z2   = (uint4*)ws; ws += align256(zbytes);
    uint4* accb = (uint4*)ws; ws += align256(zbytes);
    uint4* embb = (uint4*)ws; ws += align256(zbytes);
    unsigned* pairs = (unsigned*)ws; ws += align256((size_t)E * 4);
    int* csr_src    = (int*)ws;      ws += align256((size_t)E * 4);
    int* row_ptr    = (int*)ws;      ws += align256((size_t)(N + 1) * 4);
    int* H          = (int*)ws;      ws += align256((size_t)M * 4);
    int* S          = (int*)ws;      ws += align256((size_t)M * 4);
    int* T          = (int*)ws;      ws += align256(256 * 4);
    int* bbase      = (int*)ws;

    // --- deterministic radix CSR build (no memsets, no global atomics) ---
    block_hist_kernel<<<nblocks, 256, 0, stream>>>(col, H, E, NB, nblocks);
    scan_tile_sum_kernel<<<nt, 256, 0, stream>>>(H, T, M);
    scan_tile_offsets_kernel<<<1, 256, 0, stream>>>(T, nt);
    scan_final_kernel<<<nt, 256, 0, stream>>>(H, T, S, bbase, M, nblocks, NB, E);
    scatter_binned_kernel<<<nblocks, 256, 0, stream>>>(row, col, S, pairs, E,
                                                       NB, nblocks);
    // fine fill + fused prescale (z0, embb)
    fine_fill_kernel<<<NB, 256, 0, stream>>>(pairs, bbase, (const float4*)emb,
                                             row_ptr, csr_src, z0, embb, N, E);

    // --- layers 1,2 pull-SpMM; layer 3 fused with combine ---
    const int nodeBlocks = (N * 8 + 255) / 256;
    spmm_pull_kernel<<<nodeBlocks, 256, 0, stream>>>(row_ptr, csr_src, z0, z1, N);
    spmm_pull_kernel<<<nodeBlocks, 256, 0, stream>>>(row_ptr, csr_src, z1, z2, N);
    spmm_combine_kernel<<<nodeBlocks, 256, 0, stream>>>(row_ptr, csr_src, z2,
                                                        z1, embb, accb, N);

    // --- scoring: 2 pairs per 8-lane group ---
    const int scoreBlocks = ((P / 2) * 8 + 255) / 256;
    score_kernel<<<scoreBlocks, 256, 0, stream>>>(batch, accb, out, P);
}

// Round 9
// 252.723 us; speedup vs baseline: 1.0185x; 1.0163x over previous
//
#include <hip/hip_runtime.h>

#define DIM 64
#define BSHIFT 8                 // bucket = dst >> 8  (node range 256/bucket)
#define MAXNB 1024               // max coarse buckets (N <= 262144)
#define CHUNK 4096               // edges per block in hist/scatter passes

// ---------------------------------------------------------------------------
// bf16 helpers (OCP bf16 = top 16 bits of fp32, RNE)
// ---------------------------------------------------------------------------
__device__ inline unsigned packbf(float a, float b) {
    unsigned ua = __float_as_uint(a), ub = __float_as_uint(b);
    unsigned ra = (ua + 0x7FFFu + ((ua >> 16) & 1u)) >> 16;
    unsigned rb = (ub + 0x7FFFu + ((ub >> 16) & 1u)) >> 16;
    return ra | (rb << 16);
}
__device__ inline void unpackbf(unsigned u, float& lo, float& hi) {
    lo = __uint_as_float(u << 16);
    hi = __uint_as_float(u & 0xFFFF0000u);
}
// s[0..7] += 8 bf16 (one uint4)
__device__ inline void acc_row(const uint4 v, float* s) {
    float lo, hi;
    unpackbf(v.x, lo, hi); s[0] += lo; s[1] += hi;
    unpackbf(v.y, lo, hi); s[2] += lo; s[3] += hi;
    unpackbf(v.z, lo, hi); s[4] += lo; s[5] += hi;
    unpackbf(v.w, lo, hi); s[6] += lo; s[7] += hi;
}
// s[0..7] += m * (8 bf16)   (m = 0/1 tail mask -> fma, no branch)
__device__ inline void acc_row_m(const uint4 v, float m, float* s) {
    float lo, hi;
    unpackbf(v.x, lo, hi); s[0] = fmaf(m, lo, s[0]); s[1] = fmaf(m, hi, s[1]);
    unpackbf(v.y, lo, hi); s[2] = fmaf(m, lo, s[2]); s[3] = fmaf(m, hi, s[3]);
    unpackbf(v.z, lo, hi); s[4] = fmaf(m, lo, s[4]); s[5] = fmaf(m, hi, s[5]);
    unpackbf(v.w, lo, hi); s[6] = fmaf(m, lo, s[6]); s[7] = fmaf(m, hi, s[7]);
}

// ---------------------------------------------------------------------------
// K1: per-block bucket histogram.  H[k*nblocks + b] = count (bucket-major)
// ---------------------------------------------------------------------------
__global__ __launch_bounds__(256) void block_hist_kernel(
        const int* __restrict__ col, int* __restrict__ H, int E, int NB,
        int nblocks) {
    __shared__ int h[MAXNB];
    int tid = threadIdx.x;
    for (int k = tid; k < NB; k += 256) h[k] = 0;
    __syncthreads();
    int base = blockIdx.x * CHUNK;
    #pragma unroll
    for (int k = 0; k < CHUNK / 256; k++) {
        int e = base + tid + k * 256;
        if (e < E) atomicAdd(&h[col[e] >> BSHIFT], 1);
    }
    __syncthreads();
    for (int k = tid; k < NB; k += 256) H[(size_t)k * nblocks + blockIdx.x] = h[k];
}

// ---------------------------------------------------------------------------
// K2: per-1024-tile sums of H (raw, NOT scanned)
// ---------------------------------------------------------------------------
__global__ void scan_tile_sum_kernel(const int* __restrict__ H,
                                     int* __restrict__ T, int M) {
    int tid = threadIdx.x;
    int base = blockIdx.x * 1024 + tid * 4;
    int s = 0;
    #pragma unroll
    for (int k = 0; k < 4; k++)
        if (base + k < M) s += H[base + k];
    __shared__ int lds[256];
    lds[tid] = s;
    __syncthreads();
    for (int off = 128; off > 0; off >>= 1) {
        if (tid < off) lds[tid] += lds[tid + off];
        __syncthreads();
    }
    if (tid == 0) T[blockIdx.x] = lds[0];
}

// ---------------------------------------------------------------------------
// K3: global exclusive scan of H -> S.  Tile offset computed in-block from
// raw T[0..bid) (<=256 entries — free).  Emits bbase[k] = S[k*nblocks].
// ---------------------------------------------------------------------------
__global__ void scan_final_kernel(const int* __restrict__ H,
                                  const int* __restrict__ T,
                                  int* __restrict__ S,
                                  int* __restrict__ bbase, int M, int nblocks,
                                  int NB, int E) {
    __shared__ int lds[256];
    __shared__ int toff_sh;
    int tid = threadIdx.x;
    int bid = blockIdx.x;
    // tile offset = sum of T[0..bid)
    int tv = (tid < bid) ? T[tid] : 0;
    lds[tid] = tv;
    __syncthreads();
    for (int off = 128; off > 0; off >>= 1) {
        if (tid < off) lds[tid] += lds[tid + off];
        __syncthreads();
    }
    if (tid == 0) toff_sh = lds[0];
    __syncthreads();
    int toff = toff_sh;
    __syncthreads();

    int base = bid * 1024 + tid * 4;
    int c[4];
    int local = 0;
    #pragma unroll
    for (int k = 0; k < 4; k++) {
        c[k] = (base + k < M) ? H[base + k] : 0;
        local += c[k];
    }
    lds[tid] = local;
    __syncthreads();
    for (int off = 1; off < 256; off <<= 1) {
        int t = (tid >= off) ? lds[tid - off] : 0;
        __syncthreads();
        lds[tid] += t;
        __syncthreads();
    }
    int excl = lds[tid] - local + toff;
    #pragma unroll
    for (int k = 0; k < 4; k++) {
        int m = base + k;
        if (m < M) {
            S[m] = excl;
            if (m % nblocks == 0) bbase[m / nblocks] = excl;  // bucket start
        }
        excl += c[k];
    }
    if (bid == 0 && tid == 0) bbase[NB] = E;
}

// ---------------------------------------------------------------------------
// K4: deterministic binned scatter (bases from S — zero global atomics)
// pairs[pos] = src | (dst_local << 24)
// ---------------------------------------------------------------------------
__global__ __launch_bounds__(256) void scatter_binned_kernel(
        const int* __restrict__ row, const int* __restrict__ col,
        const int* __restrict__ S, unsigned* __restrict__ pairs, int E,
        int NB, int nblocks) {
    __shared__ unsigned stage[CHUNK];
    __shared__ int gdst[CHUNK];
    __shared__ int hist[MAXNB];   // counts -> local cursor
    __shared__ int pfx[MAXNB];    // exclusive local prefix
    __shared__ int gbase[MAXNB];  // per-(block,bucket) base (scan scratch too)
    int tid = threadIdx.x;
    int bid = blockIdx.x;
    int base = bid * CHUNK;
    int nloc = min(CHUNK, E - base);

    for (int b = tid; b < NB; b += 256) hist[b] = 0;
    __syncthreads();

    unsigned vals[CHUNK / 256];
    int keys[CHUNK / 256];
    #pragma unroll
    for (int k = 0; k < CHUNK / 256; k++) {
        int e = base + tid + k * 256;
        if (e < E) {
            int d = col[e];
            int s = row[e];
            keys[k] = d >> BSHIFT;
            vals[k] = (unsigned)s | ((unsigned)(d & 255) << 24);
            atomicAdd(&hist[keys[k]], 1);
        } else {
            keys[k] = -1;
        }
    }
    __syncthreads();

    int b0 = tid * 4;
    int c4[4];
    int loc = 0;
    #pragma unroll
    for (int k = 0; k < 4; k++) {
        c4[k] = (b0 + k < NB) ? hist[b0 + k] : 0;
        loc += c4[k];
    }
    gbase[tid] = loc;
    __syncthreads();
    for (int off = 1; off < 256; off <<= 1) {
        int t = (tid >= off) ? gbase[tid - off] : 0;
        __syncthreads();
        gbase[tid] += t;
        __syncthreads();
    }
    int excl = gbase[tid] - loc;
    #pragma unroll
    for (int k = 0; k < 4; k++) {
        if (b0 + k < NB) pfx[b0 + k] = excl;
        excl += c4[k];
    }
    __syncthreads();

    for (int b = tid; b < NB; b += 256) {
        gbase[b] = S[(size_t)b * nblocks + bid];
        hist[b] = pfx[b];
    }
    __syncthreads();

    #pragma unroll
    for (int k = 0; k < CHUNK / 256; k++) {
        if (keys[k] >= 0) {
            int slot = atomicAdd(&hist[keys[k]], 1);
            stage[slot] = vals[k];
            gdst[slot] = gbase[keys[k]] + (slot - pfx[keys[k]]);
        }
    }
    __syncthreads();

    for (int s = tid; s < nloc; s += 256) pairs[gdst[s]] = stage[s];
}

// ---------------------------------------------------------------------------
// K5: fine fill — one workgroup per bucket; LDS count/scan/cursors;
// produces row_ptr (degree = diff) and dst-grouped csr_src.
// ---------------------------------------------------------------------------
__global__ void fine_fill_kernel(const unsigned* __restrict__ pairs,
                                 const int* __restrict__ bbase,
                                 int* __restrict__ row_ptr,
                                 int* __restrict__ csr_src, int N, int E) {
    __shared__ int cnt[256];
    __shared__ int cur[256];
    int b = blockIdx.x;
    int tid = threadIdx.x;
    int beg = bbase[b], end = bbase[b + 1];
    cnt[tid] = 0;
    __syncthreads();
    for (int j = beg + tid; j < end; j += 256)
        atomicAdd(&cnt[pairs[j] >> 24], 1);
    __syncthreads();
    int v = cnt[tid];
    for (int off = 1; off < 256; off <<= 1) {
        int t = (tid >= off) ? cnt[tid - off] : 0;
        __syncthreads();
        cnt[tid] += t;
        __syncthreads();
    }
    int excl = cnt[tid] - v;
    int node = (b << BSHIFT) + tid;
    if (node < N) row_ptr[node] = beg + excl;
    cur[tid] = beg + excl;
    __syncthreads();
    for (int j = beg + tid; j < end; j += 256) {
        unsigned p = pairs[j];
        int pos = atomicAdd(&cur[p >> 24], 1);
        csr_src[pos] = (int)(p & 0xFFFFFFu);
    }
    if (b == 0 && tid == 0) row_ptr[N] = E;
}

// ---------------------------------------------------------------------------
// prescale: z0 = deg^{-1/2} * emb (bf16) AND embb = emb (bf16)
// 8-lane group per node; wide grid (self-scheduling, overlaps launch gaps)
// ---------------------------------------------------------------------------
__global__ __launch_bounds__(256) void prescale_kernel(
        const float4* __restrict__ emb4, const int* __restrict__ row_ptr,
        uint4* __restrict__ z4, uint4* __restrict__ embb, int N) {
    int t = blockIdx.x * 256 + threadIdx.x;
    int i = t >> 3;
    int gl = t & 7;
    if (i >= N) return;
    int deg = row_ptr[i + 1] - row_ptr[i];
    float wd = (deg > 0) ? rsqrtf((float)deg) : 0.0f;
    size_t eo = (size_t)i * 16 + gl * 2;
    float4 a = emb4[eo], b = emb4[eo + 1];
    size_t zo = (size_t)i * 8 + gl;
    uint4 eb;
    eb.x = packbf(a.x, a.y);
    eb.y = packbf(a.z, a.w);
    eb.z = packbf(b.x, b.y);
    eb.w = packbf(b.z, b.w);
    embb[zo] = eb;
    uint4 z;
    z.x = packbf(a.x * wd, a.y * wd);
    z.y = packbf(a.z * wd, a.w * wd);
    z.z = packbf(b.x * wd, b.y * wd);
    z.w = packbf(b.z * wd, b.w * wd);
    z4[zo] = z;
}

// ---------------------------------------------------------------------------
// software-pipelined gather-sum over one CSR row (8-lane group)
// ---------------------------------------------------------------------------
__device__ inline void row_gather_sum(const int* __restrict__ csr_src,
                                      const uint4* __restrict__ z4, int b,
                                      int e, int gl, float* s) {
    if (b >= e) return;
    int e1 = e - 1;
    int j = b;
    int i0 = csr_src[j];
    int i1 = csr_src[min(j + 1, e1)];
    int i2 = csr_src[min(j + 2, e1)];
    int i3 = csr_src[min(j + 3, e1)];
    while (j < e) {
        uint4 v0 = z4[(size_t)i0 * 8 + gl];
        uint4 v1 = z4[(size_t)i1 * 8 + gl];
        uint4 v2 = z4[(size_t)i2 * 8 + gl];
        uint4 v3 = z4[(size_t)i3 * 8 + gl];
        int jn = j + 4;
        if (jn < e) {
            i0 = csr_src[jn];
            i1 = csr_src[min(jn + 1, e1)];
            i2 = csr_src[min(jn + 2, e1)];
            i3 = csr_src[min(jn + 3, e1)];
        }
        float m1 = (j + 1 < e) ? 1.0f : 0.0f;
        float m2 = (j + 2 < e) ? 1.0f : 0.0f;
        float m3 = (j + 3 < e) ? 1.0f : 0.0f;
        acc_row(v0, s);
        acc_row_m(v1, m1, s);
        acc_row_m(v2, m2, s);
        acc_row_m(v3, m3, s);
        j = jn;
    }
}

// ---------------------------------------------------------------------------
// pull SpMM on bf16 z:  z_next[i] = (sum z[src]) / deg
// ---------------------------------------------------------------------------
__global__ __launch_bounds__(256) void spmm_pull_kernel(
        const int* __restrict__ row_ptr, const int* __restrict__ csr_src,
        const uint4* __restrict__ z4, uint4* __restrict__ znext4, int N) {
    int t = blockIdx.x * 256 + threadIdx.x;
    int i = t >> 3;
    int gl = t & 7;
    if (i >= N) return;
    int b = row_ptr[i], e = row_ptr[i + 1];
    float s[8] = {0, 0, 0, 0, 0, 0, 0, 0};
    row_gather_sum(csr_src, z4, b, e, gl, s);
    int deg = e - b;
    float wd = (deg > 0) ? rsqrtf((float)deg) : 0.0f;
    float w2 = wd * wd;
    uint4 z;
    z.x = packbf(s[0] * w2, s[1] * w2);
    z.y = packbf(s[2] * w2, s[3] * w2);
    z.z = packbf(s[4] * w2, s[5] * w2);
    z.w = packbf(s[6] * w2, s[7] * w2);
    znext4[(size_t)i * 8 + gl] = z;
}

// ---------------------------------------------------------------------------
// fused layer-3 SpMM + combine:
//   t = sum_{nbr} z2[src];  acc = embb + sqrt(deg)*(z1+z2) + wd*t   (bf16)
// ---------------------------------------------------------------------------
__global__ __launch_bounds__(256) void spmm_combine_kernel(
        const int* __restrict__ row_ptr, const int* __restrict__ csr_src,
        const uint4* __restrict__ z2, const uint4* __restrict__ z1,
        const uint4* __restrict__ embb, uint4* __restrict__ accb, int N) {
    int t = blockIdx.x * 256 + threadIdx.x;
    int i = t >> 3;
    int gl = t & 7;
    if (i >= N) return;
    int b = row_ptr[i], e = row_ptr[i + 1];
    float s[8] = {0, 0, 0, 0, 0, 0, 0, 0};
    row_gather_sum(csr_src, z2, b, e, gl, s);
    int deg = e - b;
    float wd = (deg > 0) ? rsqrtf((float)deg) : 0.0f;
    float sq = (deg > 0) ? sqrtf((float)deg) : 0.0f;
    size_t zo = (size_t)i * 8 + gl;
    uint4 a1 = z1[zo], a2 = z2[zo];
    float w[8] = {0, 0, 0, 0, 0, 0, 0, 0};
    acc_row(a1, w); acc_row(a2, w);
    uint4 eb = embb[zo];
    float em[8] = {0, 0, 0, 0, 0, 0, 0, 0};
    acc_row(eb, em);
    float r[8];
    #pragma unroll
    for (int k = 0; k < 8; k++) r[k] = em[k] + sq * w[k] + wd * s[k];
    uint4 z;
    z.x = packbf(r[0], r[1]);
    z.y = packbf(r[2], r[3]);
    z.z = packbf(r[4], r[5]);
    z.w = packbf(r[6], r[7]);
    accb[zo] = z;
}

// ---------------------------------------------------------------------------
// logits[p] = alpha^2 * dot(acc[u], acc[i])
// 8-lane group per TWO pairs (4 gathers in flight)
// ---------------------------------------------------------------------------
__global__ __launch_bounds__(256) void score_kernel(
        const int* __restrict__ batch, const uint4* __restrict__ accb,
        float* __restrict__ out, int P) {
    int t = blockIdx.x * 256 + threadIdx.x;
    int g = t >> 3;
    int gl = t & 7;
    int p0 = g * 2;
    if (p0 >= P) return;
    int p1 = min(p0 + 1, P - 1);
    int u0 = batch[(size_t)p0 * 3 + 0];
    int i0 = batch[(size_t)p0 * 3 + 1];
    int u1 = batch[(size_t)p1 * 3 + 0];
    int i1 = batch[(size_t)p1 * 3 + 1];
    uint4 a0 = accb[(size_t)u0 * 8 + gl];
    uint4 b0 = accb[(size_t)i0 * 8 + gl];
    uint4 a1 = accb[(size_t)u1 * 8 + gl];
    uint4 b1 = accb[(size_t)i1 * 8 + gl];
    float sa[8], sb[8];
    #pragma unroll
    for (int k = 0; k < 8; k++) { sa[k] = 0; sb[k] = 0; }
    acc_row(a0, sa);
    acc_row(b0, sb);
    float s0 = sa[0] * sb[0] + sa[1] * sb[1] + sa[2] * sb[2] + sa[3] * sb[3] +
               sa[4] * sb[4] + sa[5] * sb[5] + sa[6] * sb[6] + sa[7] * sb[7];
    #pragma unroll
    for (int k = 0; k < 8; k++) { sa[k] = 0; sb[k] = 0; }
    acc_row(a1, sa);
    acc_row(b1, sb);
    float s1 = sa[0] * sb[0] + sa[1] * sb[1] + sa[2] * sb[2] + sa[3] * sb[3] +
               sa[4] * sb[4] + sa[5] * sb[5] + sa[6] * sb[6] + sa[7] * sb[7];
    s0 += __shfl_xor(s0, 4, 64);
    s0 += __shfl_xor(s0, 2, 64);
    s0 += __shfl_xor(s0, 1, 64);
    s1 += __shfl_xor(s1, 4, 64);
    s1 += __shfl_xor(s1, 2, 64);
    s1 += __shfl_xor(s1, 1, 64);
    if (gl == 0) {
        out[p0] = s0 * 0.0625f;  // alpha^2, alpha = 1/(K_LAYERS+1)
        if (p0 + 1 < P) out[p0 + 1] = s1 * 0.0625f;
    }
}

extern "C" void kernel_launch(void* const* d_in, const int* in_sizes, int n_in,
                              void* d_out, int out_size, void* d_ws,
                              size_t ws_size, hipStream_t stream) {
    const float* emb = (const float*)d_in[0];
    const int* edge_index = (const int*)d_in[1];
    const int* batch = (const int*)d_in[2];
    float* out = (float*)d_out;

    const int N = in_sizes[0] / DIM;        // 200000
    const int E = in_sizes[1] / 2;          // 1250000
    const int P = out_size;                 // 4096 * 101
    const int NB = (N + 255) >> BSHIFT;     // 782 coarse buckets
    const int nblocks = (E + CHUNK - 1) / CHUNK;  // 306 edge chunks
    const int M = NB * nblocks;             // 239292 scan entries
    const int nt = (M + 1023) / 1024;       // 234 scan tiles (<=256)

    const int* row = edge_index;            // sources
    const int* col = edge_index + E;        // targets

    const size_t zbytes = (size_t)N * DIM * 2;  // bf16 row buffer (25.6 MB)

    auto align256 = [](size_t x) { return (x + 255) & ~(size_t)255; };
    char* ws = (char*)d_ws;
    uint4* z0   = (uint4*)ws; ws += align256(zbytes);
    uint4* z1   = (uint4*)ws; ws += align256(zbytes);
    uint4* z2   = (uint4*)ws; ws += align256(zbytes);
    uint4* accb = (uint4*)ws; ws += align256(zbytes);
    uint4* embb = (uint4*)ws; ws += align256(zbytes);
    unsigned* pairs = (unsigned*)ws; ws += align256((size_t)E * 4);
    int* csr_src    = (int*)ws;      ws += align256((size_t)E * 4);
    int* row_ptr    = (int*)ws;      ws += align256((size_t)(N + 1) * 4);
    int* H          = (int*)ws;      ws += align256((size_t)M * 4);
    int* S          = (int*)ws;      ws += align256((size_t)M * 4);
    int* T          = (int*)ws;      ws += align256(256 * 4);
    int* bbase      = (int*)ws;

    // --- deterministic radix CSR build (no memsets, no global atomics) ---
    block_hist_kernel<<<nblocks, 256, 0, stream>>>(col, H, E, NB, nblocks);
    scan_tile_sum_kernel<<<nt, 256, 0, stream>>>(H, T, M);
    scan_final_kernel<<<nt, 256, 0, stream>>>(H, T, S, bbase, M, nblocks, NB, E);
    scatter_binned_kernel<<<nblocks, 256, 0, stream>>>(row, col, S, pairs, E,
                                                       NB, nblocks);
    fine_fill_kernel<<<NB, 256, 0, stream>>>(pairs, bbase, row_ptr, csr_src,
                                             N, E);

    // z0 = deg^{-1/2} * emb ; embb = bf16(emb)   (wide separate kernel)
    const int nodeBlocks = (N * 8 + 255) / 256;
    prescale_kernel<<<nodeBlocks, 256, 0, stream>>>((const float4*)emb,
                                                    row_ptr, z0, embb, N);

    // --- layers 1,2 pull-SpMM; layer 3 fused with combine ---
    spmm_pull_kernel<<<nodeBlocks, 256, 0, stream>>>(row_ptr, csr_src, z0, z1, N);
    spmm_pull_kernel<<<nodeBlocks, 256, 0, stream>>>(row_ptr, csr_src, z1, z2, N);
    spmm_combine_kernel<<<nodeBlocks, 256, 0, stream>>>(row_ptr, csr_src, z2,
                                                        z1, embb, accb, N);

    // --- scoring: 2 pairs per 8-lane group ---
    const int scoreBlocks = ((P / 2) * 8 + 255) / 256;
    score_kernel<<<scoreBlocks, 256, 0, stream>>>(batch, accb, out, P);
}